// Round 8
// baseline (1346.549 us; speedup 1.0000x reference)
//
#include <hip/hip_runtime.h>
#include <hip/hip_cooperative_groups.h>
#include <cstdint>
#include <cstddef>

namespace cg = cooperative_groups;

// DSDHLoss: faithful DCC loop on bitmask representation.
// B (+-1) -> 64-bit column masks + row-major bit-planes; Ybuf (0/1) -> masks.
// S=B B^T and R=B Y^T via popcount (exact integers == fp32 reference values).
// Margins: GS decides sign(55*U + O(1e-2)) -> fp16 in all correction terms
// is far below decision margins.
// R8: the whole 10-iteration DCC loop is ONE cooperative kernel (512 blocks,
//   grid.sync between k1/k2a/k3 phases). R7 had 30 loop launches (18 of them
//   skipped no-ops); boundary cost dominated. Convergence break is uniform
//   (one global int) -> skipped iterations cost zero. Phase bodies shared
//   (__device__) with classic kernels; hipLaunchCooperativeKernel failure
//   falls back to the classic 30-launch loop.
// k1: padded bit-rows, compile-time chunks, register popcounts.
// k2a: Neumann solve (4 iters), fp16 X broadcasts, W written from registers.
// k3: G = W W^T via in-kernel MFMA on staged sWt (R7); X = W.y - G.b per-wave
//   MFMA (R4); packed-fp16 qx state, fixed-trip packed repair (R6).
// l1: MFMA (16x16x32 f16) GEMM u @ Ucols with softplus epilogue.
// l2: 32-block partials + 1-wave finalize (R7).
// R1: convergence early-out (cflags in ws bytes [0,64)).
// R3: build_colmasks 1 col/thread; popcY folded into build_rows atomics.
// R5 LESSON (kept): no variable-trip inner loops / runtime-indexed
//   ext_vector arrays in k3's sweep -> scratch spill (105MB FETCH, 130x).

#define NT 100000
#define WPR 1568      // padded u64 words per bit-row (1563 real + 5 zero)
#define NWREAL 1563
#define NGRPP 1568    // padded group count
#define NJB 1563      // ceil(NT/64) l1 blocks
#define ETA_MU 55.0f
#define LAM 0.1f

typedef unsigned long long u64;
typedef _Float16 half8 __attribute__((ext_vector_type(8)));
typedef _Float16 half4 __attribute__((ext_vector_type(4)));
typedef float float4v __attribute__((ext_vector_type(4)));

struct __attribute__((aligned(16))) K2aS {
  short sEi[4096];
  _Float16 sXa[64 * 32];
  _Float16 sXb[64 * 32];
};
struct __attribute__((aligned(16))) K3S {
  _Float16 sWt[64 * 136];   // W^T [i][c], c in [0,128), 0-pad c>=100
  _Float16 sGr[64 * 72];    // G rows [i][k] (MFMA-computed)
  float sGd[64];            // diag fp32
  _Float16 sQx[4 * 64 * 72]; // per-wave exchange [jl][i]
};
union __attribute__((aligned(16))) LoopS { K2aS a; K3S b; };

__device__ inline u64 transpose64(u64 x, int lane) {
  const u64 ms[6] = {0x5555555555555555ull,0x3333333333333333ull,0x0F0F0F0F0F0F0F0Full,
                     0x00FF00FF00FF00FFull,0x0000FFFF0000FFFFull,0x00000000FFFFFFFFull};
#pragma unroll
  for (int si = 0; si < 6; ++si) {
    int s = 1 << si;
    u64 m = ms[si];
    u64 y = __shfl_xor(x, s, 64);
    if ((lane & s) == 0) x = (x & m) | ((y & m) << s);
    else                 x = (x & ~m) | ((y & ~m) >> s);
  }
  return x;
}

__device__ inline double wave_reduce_f64(double v) {
#pragma unroll
  for (int off = 32; off > 0; off >>= 1) v += __shfl_down(v, off, 64);
  return v;
}

// ---------------- phase bodies (shared: classic kernels + fused loop) ------

__device__ __forceinline__ void k1_body(
    int k, int q, const u64* __restrict__ Brow, const u64* __restrict__ Yrow,
    int* __restrict__ S_part, int* __restrict__ R_part) {
  int w0 = q * 196;
  int wv = threadIdx.x >> 6, lane = threadIdx.x & 63;
  u64 tmask = (lane < 4) ? ~0ull : 0ull;
  const u64* bk = Brow + (size_t)k * WPR + w0;
  u64 b0 = bk[lane], b1 = bk[lane + 64], b2 = bk[lane + 128];
  u64 b3 = bk[192 + (lane & 3)] & tmask;
  int sS[16];
#pragma unroll
  for (int m = 0; m < 16; ++m) {
    const u64* br = Brow + (size_t)(4 * m + wv) * WPR + w0;
    u64 x0 = br[lane], x1 = br[lane + 64], x2 = br[lane + 128];
    u64 x3 = br[192 + (lane & 3)] & tmask;
    sS[m] = __popcll(x0 ^ b0) + __popcll(x1 ^ b1) +
            __popcll(x2 ^ b2) + __popcll(x3 ^ b3);
  }
  int sR[25];
#pragma unroll
  for (int m = 0; m < 25; ++m) {
    const u64* yr = Yrow + (size_t)(4 * m + wv) * WPR + w0;
    u64 x0 = yr[lane], x1 = yr[lane + 64], x2 = yr[lane + 128];
    u64 x3 = yr[192 + (lane & 3)] & tmask;
    sR[m] = __popcll(x0 & b0) + __popcll(x1 & b1) +
            __popcll(x2 & b2) + __popcll(x3 & b3);
  }
#pragma unroll
  for (int off = 32; off > 0; off >>= 1) {
#pragma unroll
    for (int m = 0; m < 16; ++m) sS[m] += __shfl_down(sS[m], off, 64);
#pragma unroll
    for (int m = 0; m < 25; ++m) sR[m] += __shfl_down(sR[m], off, 64);
  }
  if (lane == 0) {
#pragma unroll
    for (int m = 0; m < 16; ++m)
      S_part[q * 4096 + k * 64 + 4 * m + wv] = sS[m];
#pragma unroll
    for (int m = 0; m < 25; ++m)
      R_part[q * 6400 + k * 100 + 4 * m + wv] = sR[m];
  }
}

__device__ __forceinline__ void k2a_body(
    int b, const int* __restrict__ S_part, const int* __restrict__ R_part,
    const int* __restrict__ popcY, float* __restrict__ Wr,
    float* __restrict__ Wc, K2aS* __restrict__ s) {
  int tid = threadIdx.x;
  int wv = tid >> 6, k = tid & 63;
  const int qbase_t[4] = {0, 7, 14, 20};
  const int qcnt_t[4]  = {7, 7, 6, 6};
  int qbase = qbase_t[b], Q = qcnt_t[b];
  const int off7[4] = {0, 2, 4, 6}, cnt7[4] = {2, 2, 2, 1};
  const int off6[4] = {0, 2, 4, 5}, cnt6[4] = {2, 2, 1, 1};
  int woff = (Q == 7) ? off7[wv] : off6[wv];
  int wcnt = (Q == 7) ? cnt7[wv] : cnt6[wv];
  const float alpha = 1.0f / (100000.0f + LAM);
  for (int e = tid; e < 4096; e += 256) {
    int kk = e >> 6, ll = e & 63;
    int mm = 0;
#pragma unroll
    for (int qq = 0; qq < 8; ++qq) mm += S_part[qq * 4096 + e];
    int v = (kk == ll) ? 0 : (NT - 2 * mm);
    v = v > 32767 ? 32767 : (v < -32767 ? -32767 : v);
    s->sEi[kk * 64 + (ll ^ (kk & 31))] = (short)v;
  }
  float4 rr4[2], xf[2];
#pragma unroll
  for (int q = 0; q < 2; ++q) {
    if (q < wcnt) {
      float tmp[4];
#pragma unroll
      for (int e4 = 0; e4 < 4; ++e4) {
        int cg2 = 4 * (qbase + woff + q) + e4;
        float rv = 0.0f;
        if (cg2 < 100) {
          int rr = 0;
#pragma unroll
          for (int qq = 0; qq < 8; ++qq) rr += R_part[qq * 6400 + k * 100 + cg2];
          rv = (float)(2 * rr - popcY[cg2]);
        }
        tmp[e4] = rv;
      }
      rr4[q] = make_float4(tmp[0], tmp[1], tmp[2], tmp[3]);
      xf[q] = make_float4(alpha * tmp[0], alpha * tmp[1],
                          alpha * tmp[2], alpha * tmp[3]);
    }
  }
  if (wcnt == 2) {
    half8 h;
    h[0] = (_Float16)xf[0].x; h[1] = (_Float16)xf[0].y;
    h[2] = (_Float16)xf[0].z; h[3] = (_Float16)xf[0].w;
    h[4] = (_Float16)xf[1].x; h[5] = (_Float16)xf[1].y;
    h[6] = (_Float16)xf[1].z; h[7] = (_Float16)xf[1].w;
    *(half8*)&s->sXa[k * 32 + 4 * woff] = h;
  } else {
    half4 h;
    h[0] = (_Float16)xf[0].x; h[1] = (_Float16)xf[0].y;
    h[2] = (_Float16)xf[0].z; h[3] = (_Float16)xf[0].w;
    *(half4*)&s->sXa[k * 32 + 4 * woff] = h;
  }
  __syncthreads();
  _Float16* Xs = s->sXa;
  _Float16* Xd = s->sXb;
  for (int it2 = 0; it2 < 4; ++it2) {
    float4 a4[2];
#pragma unroll
    for (int q = 0; q < 2; ++q)
      if (q < wcnt) a4[q] = rr4[q];
    if (wcnt == 2) {
      for (int l = 0; l < 64; ++l) {
        float ev = (float)s->sEi[k * 64 + (l ^ (k & 31))];
        half8 x8 = *(const half8*)&Xs[l * 32 + 4 * woff];
        a4[0].x -= ev * (float)x8[0]; a4[0].y -= ev * (float)x8[1];
        a4[0].z -= ev * (float)x8[2]; a4[0].w -= ev * (float)x8[3];
        a4[1].x -= ev * (float)x8[4]; a4[1].y -= ev * (float)x8[5];
        a4[1].z -= ev * (float)x8[6]; a4[1].w -= ev * (float)x8[7];
      }
    } else {
      for (int l = 0; l < 64; ++l) {
        float ev = (float)s->sEi[k * 64 + (l ^ (k & 31))];
        half4 x4 = *(const half4*)&Xs[l * 32 + 4 * woff];
        a4[0].x -= ev * (float)x4[0]; a4[0].y -= ev * (float)x4[1];
        a4[0].z -= ev * (float)x4[2]; a4[0].w -= ev * (float)x4[3];
      }
    }
#pragma unroll
    for (int q = 0; q < 2; ++q) {
      if (q < wcnt) {
        xf[q] = make_float4(alpha * a4[q].x, alpha * a4[q].y,
                            alpha * a4[q].z, alpha * a4[q].w);
      }
    }
    if (it2 < 3) {
      if (wcnt == 2) {
        half8 h;
        h[0] = (_Float16)xf[0].x; h[1] = (_Float16)xf[0].y;
        h[2] = (_Float16)xf[0].z; h[3] = (_Float16)xf[0].w;
        h[4] = (_Float16)xf[1].x; h[5] = (_Float16)xf[1].y;
        h[6] = (_Float16)xf[1].z; h[7] = (_Float16)xf[1].w;
        *(half8*)&Xd[k * 32 + 4 * woff] = h;
      } else {
        half4 h;
        h[0] = (_Float16)xf[0].x; h[1] = (_Float16)xf[0].y;
        h[2] = (_Float16)xf[0].z; h[3] = (_Float16)xf[0].w;
        *(half4*)&Xd[k * 32 + 4 * woff] = h;
      }
      __syncthreads();
      _Float16* t = Xs; Xs = Xd; Xd = t;
    }
  }
#pragma unroll
  for (int q = 0; q < 2; ++q) {
    if (q < wcnt) {
      float v4[4] = {xf[q].x, xf[q].y, xf[q].z, xf[q].w};
#pragma unroll
      for (int e4 = 0; e4 < 4; ++e4) {
        int cg2 = 4 * (qbase + woff + q) + e4;
        if (cg2 < 100) {
          Wr[k * 100 + cg2] = v4[e4];
          Wc[cg2 * 64 + k] = v4[e4];
        }
      }
    }
  }
}

__device__ __forceinline__ void k3_body(
    int bid, int it, const float* __restrict__ U, const float* __restrict__ u,
    const signed char* __restrict__ owner, const float* __restrict__ Wc,
    u64* __restrict__ Bmask, u64* __restrict__ Brow,
    const u64* __restrict__ Ymask, int* __restrict__ cflags,
    K3S* __restrict__ s) {
  int tid = threadIdx.x;
  for (int t = tid; t < 8192; t += 256) {
    int i = t & 63, c = t >> 6;
    s->sWt[i * 136 + c] = (c < 100) ? (_Float16)Wc[c * 64 + i] : (_Float16)0.0f;
  }
  __syncthreads();
  int wv = tid >> 6, lane = tid & 63;
  int g = bid * 4 + wv;
  int n15 = lane & 15, quad = lane >> 4;
  int j = g * 64 + lane;
  bool act = j < NT;
  int jc = act ? j : NT - 1;
  u64 bm = Bmask[jc];
  u64 y0 = Ymask[2 * jc], y1 = Ymask[2 * jc + 1];
  half8 aW[4][4];
#pragma unroll
  for (int mt = 0; mt < 4; ++mt) {
    int rb = mt * 16 + n15;
#pragma unroll
    for (int kt = 0; kt < 4; ++kt)
      aW[mt][kt] = *(const half8*)&s->sWt[rb * 136 + kt * 32 + quad * 8];
  }
  half8 aWv[4];
  {
    int rb = wv * 16 + n15;
#pragma unroll
    for (int kt = 0; kt < 4; ++kt)
      aWv[kt] = *(const half8*)&s->sWt[rb * 136 + kt * 32 + quad * 8];
  }
#pragma unroll
  for (int nt = 0; nt < 4; ++nt) {
    float4v c = {0.f, 0.f, 0.f, 0.f};
#pragma unroll
    for (int kt = 0; kt < 4; ++kt)
      c = __builtin_amdgcn_mfma_f32_16x16x32_f16(aWv[kt], aW[nt][kt], c, 0, 0, 0);
#pragma unroll
    for (int r = 0; r < 4; ++r) {
      int gi = wv * 16 + quad * 4 + r;
      int gk = nt * 16 + n15;
      s->sGr[gi * 72 + gk] = (_Float16)c[r];
      if (gk == gi) s->sGd[gi] = c[r];
    }
  }
  __syncthreads();   // G complete for all waves
  half8 aG[4][2];
#pragma unroll
  for (int mt = 0; mt < 4; ++mt) {
    int rb = mt * 16 + n15;
#pragma unroll
    for (int kt = 0; kt < 2; ++kt)
      aG[mt][kt] = *(const half8*)&s->sGr[rb * 72 + kt * 32 + quad * 8];
  }
  _Float16* xq = &s->sQx[wv * 64 * 72];
  int c0q = quad * 8;
#pragma unroll
  for (int nt = 0; nt < 4; ++nt) {
    int src = nt * 16 + n15;
    u64 cy0 = __shfl(y0, src, 64);
    u64 cy1 = __shfl(y1, src, 64);
    u64 cbm = __shfl(bm, src, 64);
    half8 yf[4], bf[2];
#pragma unroll
    for (int kt = 0; kt < 2; ++kt) {           // classes [0,64)
      int c0 = kt * 32 + c0q;
      u64 w = cy0 >> c0;
      w |= (c0 ? (cy1 << ((64 - c0) & 63)) : 0ull);
#pragma unroll
      for (int e = 0; e < 8; ++e)
        yf[kt][e] = ((w >> e) & 1ull) ? (_Float16)1.0f : (_Float16)0.0f;
    }
#pragma unroll
    for (int kt = 2; kt < 4; ++kt) {           // classes [64,128), >=100 zero
      int c0 = (kt - 2) * 32 + c0q;
      u64 w = cy1 >> c0;
#pragma unroll
      for (int e = 0; e < 8; ++e)
        yf[kt][e] = ((w >> e) & 1ull) ? (_Float16)1.0f : (_Float16)0.0f;
    }
#pragma unroll
    for (int kt = 0; kt < 2; ++kt) {           // -b: bit -> -1, else +1
      int c0 = kt * 32 + c0q;
      u64 w = cbm >> c0;
#pragma unroll
      for (int e = 0; e < 8; ++e)
        bf[kt][e] = ((w >> e) & 1ull) ? (_Float16)-1.0f : (_Float16)1.0f;
    }
#pragma unroll
    for (int mt = 0; mt < 4; ++mt) {
      float4v c = {0.f, 0.f, 0.f, 0.f};
#pragma unroll
      for (int kt = 0; kt < 4; ++kt)
        c = __builtin_amdgcn_mfma_f32_16x16x32_f16(aW[mt][kt], yf[kt], c, 0, 0, 0);
#pragma unroll
      for (int kt = 0; kt < 2; ++kt)
        c = __builtin_amdgcn_mfma_f32_16x16x32_f16(aG[mt][kt], bf[kt], c, 0, 0, 0);
      half4 hs;
      hs[0] = (_Float16)c[0]; hs[1] = (_Float16)c[1];
      hs[2] = (_Float16)c[2]; hs[3] = (_Float16)c[3];
      *(half4*)&xq[(nt * 16 + n15) * 72 + mt * 16 + quad * 4] = hs;
    }
  }
  // wave-internal exchange: compiler-inserted lgkmcnt orders write->read
  int ow = owner[jc];
  float p[64];
  if (ow >= 0) {
#pragma unroll
    for (int i = 0; i < 64; ++i) p[i] = ETA_MU * u[ow * 64 + i];
  } else {
#pragma unroll
    for (int i = 0; i < 64; ++i) p[i] = ETA_MU * U[(size_t)i * NT + jc];
  }
  half8 qx[8];
#pragma unroll
  for (int t = 0; t < 8; ++t)
    qx[t] = *(const half8*)&xq[lane * 72 + t * 8];
  // sequential GS sweep; packed fixed-trip repair on flips (R6 shape)
  u64 cm = bm;
#pragma unroll
  for (int i = 0; i < 64; ++i) {
    bool ob = (cm >> i) & 1ull;
    float val = p[i] + (float)qx[i >> 3][i & 7] + (ob ? s->sGd[i] : -s->sGd[i]);
    bool nb = val > 0.0f;
    bool ch = (nb != ob);
    if (__any(ch)) {
      _Float16 dl = ch ? (nb ? (_Float16)2.0f : (_Float16)-2.0f) : (_Float16)0.0f;
#pragma unroll
      for (int t = 0; t < 8; ++t) {
        half8 gr = *(const half8*)&s->sGr[i * 72 + t * 8];   // uniform broadcast
        qx[t] -= gr * dl;
      }
      if (ch) cm ^= (1ull << i);
    }
  }
  u64 nm = act ? cm : 0ull;
  bool chg = act && (nm != bm);
  if (__any(chg) && lane == 0) cflags[it] = 1;
  if (act) Bmask[j] = nm;
  u64 tb = transpose64(nm, lane);
  Brow[(size_t)lane * WPR + g] = tb;
}

// ---------------- prologue kernels ----------------------------------------

__global__ __launch_bounds__(256) void build_colmasks(
    const float* __restrict__ B, const float* __restrict__ Ybuf,
    u64* __restrict__ Bmask, u64* __restrict__ Ymask,
    signed char* __restrict__ owner, int* __restrict__ cflags) {
  if (blockIdx.x == 0 && threadIdx.x < 16) cflags[threadIdx.x] = 0;
  int j = blockIdx.x * 256 + threadIdx.x;
  if (j >= NT) return;
  owner[j] = (signed char)-1;
  u64 bm = 0;
#pragma unroll
  for (int i = 0; i < 64; ++i)
    bm |= ((u64)(B[(size_t)i * NT + j] > 0.0f)) << i;
  u64 m0 = 0, m1 = 0;
#pragma unroll
  for (int c = 0; c < 64; ++c)
    m0 |= ((u64)(Ybuf[(size_t)c * NT + j] > 0.5f)) << c;
#pragma unroll
  for (int c = 64; c < 100; ++c)
    m1 |= ((u64)(Ybuf[(size_t)c * NT + j] > 0.5f)) << (c - 64);
  Bmask[j] = bm;
  Ymask[2 * j] = m0;
  Ymask[2 * j + 1] = m1;
}

__global__ void scatter_y(const float* __restrict__ y, const int* __restrict__ ind,
                          u64* __restrict__ Ymask, u64* __restrict__ ybatch,
                          signed char* __restrict__ owner, int* __restrict__ popcY) {
  int b = threadIdx.x;
  if (b >= 128) return;
  if (b < 100) popcY[b] = 0;
  u64 m0 = 0, m1 = 0;
  for (int c = 0; c < 100; ++c) {
    bool v = y[b * 100 + c] > 0.5f;
    if (c < 64) m0 |= ((u64)v) << c;
    else        m1 |= ((u64)v) << (c - 64);
  }
  ybatch[2 * b] = m0;
  ybatch[2 * b + 1] = m1;
  int col = ind[b];
  Ymask[2 * col] = m0;
  Ymask[2 * col + 1] = m1;
  owner[col] = (signed char)b;
}

__global__ __launch_bounds__(256) void build_rows(
    const u64* __restrict__ Bmask, const u64* __restrict__ Ymask,
    u64* __restrict__ Brow, u64* __restrict__ Yrow, int* __restrict__ popcY) {
  int g = blockIdx.x * 4 + (threadIdx.x >> 6);
  int lane = threadIdx.x & 63;
  if (g >= NGRPP) return;
  int j = g * 64 + lane;
  bool act = j < NT;
  u64 bm = act ? Bmask[j] : 0ull;
  u64 y0 = act ? Ymask[2 * j] : 0ull;
  u64 y1 = act ? Ymask[2 * j + 1] : 0ull;
  u64 tb = transpose64(bm, lane);
  Brow[(size_t)lane * WPR + g] = tb;
  u64 t0 = transpose64(y0, lane);
  Yrow[(size_t)lane * WPR + g] = t0;
  atomicAdd(&popcY[lane], (int)__popcll(t0));
  u64 t1 = transpose64(y1, lane);
  if (lane < 36) {
    Yrow[(size_t)(64 + lane) * WPR + g] = t1;
    atomicAdd(&popcY[64 + lane], (int)__popcll(t1));
  }
}

// ---------------- fused cooperative DCC loop ------------------------------

__global__ __launch_bounds__(256, 2) void dcc_loop(
    u64* __restrict__ Brow, const u64* __restrict__ Yrow,
    int* __restrict__ S_part, int* __restrict__ R_part,
    const int* __restrict__ popcY, float* __restrict__ Wr,
    float* __restrict__ Wc, const float* __restrict__ U,
    const float* __restrict__ u, const signed char* __restrict__ owner,
    u64* __restrict__ Bmask, const u64* __restrict__ Ymask,
    int* __restrict__ cflags) {
  cg::grid_group grid = cg::this_grid();
  __shared__ LoopS sm;
  int bid = blockIdx.x;
  for (int it = 0; it < 10; ++it) {
    if (it > 0 && ((volatile int*)cflags)[it - 1] == 0) break;  // uniform
    k1_body(bid & 63, bid >> 6, Brow, Yrow, S_part, R_part);
    grid.sync();
    if (bid < 4) k2a_body(bid, S_part, R_part, popcY, Wr, Wc, &sm.a);
    grid.sync();
    if (bid < 392) k3_body(bid, it, U, u, owner, Wc, Bmask, Brow, Ymask,
                           cflags, &sm.b);
    grid.sync();
  }
}

// ---------------- classic fallback kernels (same bodies) ------------------

__global__ __launch_bounds__(256, 4) void k1_sr(
    const u64* __restrict__ Brow, const u64* __restrict__ Yrow,
    int* __restrict__ S_part, int* __restrict__ R_part,
    int it, const int* __restrict__ cflags) {
  if (it > 0 && cflags[it - 1] == 0) return;
  k1_body(blockIdx.x, blockIdx.y, Brow, Yrow, S_part, R_part);
}

__global__ __launch_bounds__(256, 1) void k2a_solve(
    const int* __restrict__ S_part, const int* __restrict__ R_part,
    const int* __restrict__ popcY, float* __restrict__ Wr,
    float* __restrict__ Wc, int it, const int* __restrict__ cflags) {
  if (it > 0 && cflags[it - 1] == 0) return;
  __shared__ K2aS s;
  k2a_body(blockIdx.x, S_part, R_part, popcY, Wr, Wc, &s);
}

__global__ __launch_bounds__(256, 2) void k3_gs(
    const float* __restrict__ U, const float* __restrict__ u,
    const signed char* __restrict__ owner, const float* __restrict__ Wc,
    u64* __restrict__ Bmask, u64* __restrict__ Brow,
    const u64* __restrict__ Ymask, int it, int* __restrict__ cflags) {
  if (it > 0 && cflags[it - 1] == 0) return;
  __shared__ K3S s;
  k3_body(blockIdx.x, it, U, u, owner, Wc, Bmask, Brow, Ymask, cflags, &s);
}

// ---------------- epilogue kernels ----------------------------------------

__global__ __launch_bounds__(256, 4) void l1_like(
    const float* __restrict__ U, const float* __restrict__ u,
    const signed char* __restrict__ owner, const u64* __restrict__ Ymask,
    const u64* __restrict__ ybatch, double* __restrict__ partial) {
  __shared__ _Float16 shu[8192];   // u fp16, row b: k8 stored at (k8 ^ (b&7))
  __shared__ u64 sy[256];
  __shared__ double wred[4];
  int tid = threadIdx.x;
  for (int e = tid; e < 1024; e += 256) {
    int b = e >> 3, k8 = e & 7;
    const float4* src = (const float4*)&u[b * 64 + k8 * 8];
    float4 f0 = src[0], f1 = src[1];
    half8 h;
    h[0] = (_Float16)f0.x; h[1] = (_Float16)f0.y;
    h[2] = (_Float16)f0.z; h[3] = (_Float16)f0.w;
    h[4] = (_Float16)f1.x; h[5] = (_Float16)f1.y;
    h[6] = (_Float16)f1.z; h[7] = (_Float16)f1.w;
    *(half8*)&shu[b * 64 + ((k8 ^ (b & 7)) * 8)] = h;
  }
  if (tid < 256) sy[tid] = ybatch[tid];
  __syncthreads();
  int wv = tid >> 6, lane = tid & 63;
  int n = lane & 15, q = lane >> 4;
  int j = blockIdx.x * 64 + wv * 16 + n;
  bool actj = j < NT;
  int jc = actj ? j : NT - 1;
  int ow = owner[jc];
  half8 bf0, bf1;
#pragma unroll
  for (int t = 0; t < 8; ++t) {
    int k = q * 8 + t;
    bf0[t] = (_Float16)U[(size_t)k * NT + jc];
    bf1[t] = (_Float16)U[(size_t)(k + 32) * NT + jc];
  }
  if (ow >= 0) {
#pragma unroll
    for (int t = 0; t < 8; ++t) {
      bf0[t] = (_Float16)u[ow * 64 + q * 8 + t];
      bf1[t] = (_Float16)u[ow * 64 + 32 + q * 8 + t];
    }
  }
  u64 ym0 = Ymask[2 * jc], ym1 = Ymask[2 * jc + 1];
  float lsum = 0.0f;
#pragma unroll
  for (int t8 = 0; t8 < 8; ++t8) {
    int brow = t8 * 16 + n;
    half8 a0 = *(const half8*)&shu[brow * 64 + ((q ^ (brow & 7)) * 8)];
    half8 a1 = *(const half8*)&shu[brow * 64 + (((q + 4) ^ (brow & 7)) * 8)];
    float4v c = {0.f, 0.f, 0.f, 0.f};
    c = __builtin_amdgcn_mfma_f32_16x16x32_f16(a0, bf0, c, 0, 0, 0);
    c = __builtin_amdgcn_mfma_f32_16x16x32_f16(a1, bf1, c, 0, 0, 0);
#pragma unroll
    for (int r = 0; r < 4; ++r) {
      int b = t8 * 16 + q * 4 + r;
      float ip = 0.5f * c[r];
      u64 yb0 = sy[2 * b], yb1 = sy[2 * b + 1];
      bool s = ((yb0 & ym0) | (yb1 & ym1)) != 0ull;
      float a = fabsf(ip);
      lsum += __logf(1.0f + __expf(-a)) + fmaxf(ip, 0.0f) - (s ? ip : 0.0f);
    }
  }
  if (!actj) lsum = 0.0f;
  double lsd = wave_reduce_f64((double)lsum);
  if (lane == 0) wred[wv] = lsd;
  __syncthreads();
  if (tid == 0)
    partial[blockIdx.x] = wred[0] + wred[1] + wred[2] + wred[3];
}

__global__ __launch_bounds__(256) void l2_part(
    const float* __restrict__ Wr, const float* __restrict__ y,
    const int* __restrict__ ind, const u64* __restrict__ Bmask,
    const double* __restrict__ partial, double* __restrict__ part3) {
  __shared__ float sw[6400];
  __shared__ u64 sbm[128];
  __shared__ double dred[12];
  int tid = threadIdx.x, bid = blockIdx.x;
  for (int t = tid; t < 6400; t += 256) sw[t] = Wr[t];
  if (tid < 128) sbm[tid] = Bmask[ind[tid]];
  __syncthreads();
  double cls = 0.0, regs = 0.0, l1s = 0.0;
  int e0 = bid * 400;                      // 32 x 400 = 12800
  for (int e = e0 + tid; e < e0 + 400; e += 256) {
    int c = e >> 7, b = e & 127;
    u64 bm = sbm[b];
    float s = 0.0f;
#pragma unroll
    for (int i = 0; i < 64; ++i) {
      float w = sw[i * 100 + c];
      s += ((bm >> i) & 1ull) ? w : -w;
    }
    float d = y[b * 100 + c] - s;
    cls += (double)(d * d);
  }
  int r0 = bid * 200;                      // 32 x 200 = 6400
  for (int e = r0 + tid; e < r0 + 200; e += 256) {
    float w = sw[e];
    regs += (double)(w * w);
  }
  int t = bid * 256 + tid;                 // 32 x 256 = 8192 >= NJB
  if (t < NJB) l1s = partial[t];
  cls = wave_reduce_f64(cls);
  regs = wave_reduce_f64(regs);
  l1s = wave_reduce_f64(l1s);
  int wv = tid >> 6;
  if ((tid & 63) == 0) { dred[wv] = cls; dred[4 + wv] = regs; dred[8 + wv] = l1s; }
  __syncthreads();
  if (tid == 0) {
    part3[bid * 4 + 0] = dred[0] + dred[1] + dred[2] + dred[3];
    part3[bid * 4 + 1] = dred[4] + dred[5] + dred[6] + dred[7];
    part3[bid * 4 + 2] = dred[8] + dred[9] + dred[10] + dred[11];
  }
}

__global__ void l2_fin2(const double* __restrict__ part3,
                        float* __restrict__ out) {
  int tid = threadIdx.x;   // 64 threads
  double c = 0.0, r = 0.0, l = 0.0;
  if (tid < 32) {
    c = part3[tid * 4 + 0];
    r = part3[tid * 4 + 1];
    l = part3[tid * 4 + 2];
  }
  c = wave_reduce_f64(c);
  r = wave_reduce_f64(r);
  l = wave_reduce_f64(l);
  if (tid == 0)
    out[0] = (float)(l * (1.0 / 12800000.0) + c * (1.0 / 12800.0) +
                     r * (0.1 / 6400.0));
}

extern "C" void kernel_launch(void* const* d_in, const int* in_sizes, int n_in,
                              void* d_out, int out_size, void* d_ws, size_t ws_size,
                              hipStream_t stream) {
  const float* u    = (const float*)d_in[0];
  const float* y    = (const float*)d_in[1];
  const int*   ind  = (const int*)d_in[2];
  const float* U    = (const float*)d_in[3];
  const float* B    = (const float*)d_in[4];
  const float* Ybuf = (const float*)d_in[5];
  char* ws = (char*)d_ws;
  int* cflags        = (int*)ws;               // 16 ints in bytes [0,64)
  u64* Bmask         = (u64*)(ws + 256);
  u64* Ymask         = (u64*)(ws + 800256);
  u64* Brow          = (u64*)(ws + 2400256);
  u64* Yrow          = (u64*)(ws + 3203072);
  u64* ybatch        = (u64*)(ws + 4457472);
  int* popcY         = (int*)(ws + 4459520);
  int* S_part        = (int*)(ws + 4460032);   // 8*4096 ints
  int* R_part        = (int*)(ws + 4591104);   // 8*6400 ints
  float* Wr          = (float*)(ws + 4795904);
  float* Wc          = (float*)(ws + 4821504);
  double* part3      = (double*)(ws + 4847104); // 32*4 doubles
  signed char* owner = (signed char*)(ws + 4863488);
  double* partial    = (double*)(ws + 4963520); // NJB doubles

  build_colmasks<<<391, 256, 0, stream>>>(B, Ybuf, Bmask, Ymask, owner, cflags);
  scatter_y<<<1, 128, 0, stream>>>(y, ind, Ymask, ybatch, owner, popcY);
  build_rows<<<392, 256, 0, stream>>>(Bmask, Ymask, Brow, Yrow, popcY);

  void* args[] = {(void*)&Brow, (void*)&Yrow, (void*)&S_part, (void*)&R_part,
                  (void*)&popcY, (void*)&Wr, (void*)&Wc, (void*)&U, (void*)&u,
                  (void*)&owner, (void*)&Bmask, (void*)&Ymask, (void*)&cflags};
  hipError_t ce = hipLaunchCooperativeKernel(dcc_loop, dim3(512), dim3(256),
                                             args, 0, stream);
  if (ce != hipSuccess) {
    // fallback: classic 30-launch loop (bit-identical bodies)
    for (int it = 0; it < 10; ++it) {
      k1_sr<<<dim3(64, 8), 256, 0, stream>>>(Brow, Yrow, S_part, R_part, it, cflags);
      k2a_solve<<<4, 256, 0, stream>>>(S_part, R_part, popcY, Wr, Wc, it, cflags);
      k3_gs<<<392, 256, 0, stream>>>(U, u, owner, Wc, Bmask, Brow, Ymask, it, cflags);
    }
  }

  l1_like<<<NJB, 256, 0, stream>>>(U, u, owner, Ymask, ybatch, partial);
  l2_part<<<32, 256, 0, stream>>>(Wr, y, ind, Bmask, partial, part3);
  l2_fin2<<<1, 64, 0, stream>>>(part3, (float*)d_out);
}

// Round 9
// 496.010 us; speedup vs baseline: 2.7148x; 2.7148x over previous
//
#include <hip/hip_runtime.h>
#include <cstdint>
#include <cstddef>

// DSDHLoss: faithful DCC loop on bitmask representation.
// B (+-1) -> 64-bit column masks + row-major bit-planes; Ybuf (0/1) -> masks.
// S=B B^T and R=B Y^T via popcount (exact integers == fp32 reference values).
// Margins: GS decides sign(55*U + O(1e-2)) -> fp16 in all correction terms
// is far below decision margins.
// R9: REVERT R8's cooperative fusion (grid.sync on 8-XCD MI355X costs tens
//   of us per sync; dcc_loop paid ~3 syncs x every iteration = 1152us vs
//   classic 30-launch loop's ~150us for the same work). Classic loop + the
//   R1 cflags skip (empty launch ~2us) is the right structure.
//   NEW: prologue fused 3->2 kernels: scatter_pre (1 block: ybatch, colmap,
//   zero popcY/cflags) + build_all (392 blocks: colmasks with inline
//   scatter substitution via LDS colmap lookup, owner, and in-register
//   transpose -> Brow/Yrow/popcY). Saves a launch + mask round-trip.
// k1: padded bit-rows, compile-time chunks, register popcounts.
// k2a: Neumann solve (4 iters), fp16 X broadcasts, W written from registers.
// k3: G = W W^T via in-kernel MFMA on staged sWt (R7); X = W.y - G.b per-wave
//   MFMA (R4); packed-fp16 qx state, fixed-trip packed repair (R6).
// l1: MFMA (16x16x32 f16) GEMM u @ Ucols with softplus epilogue.
// l2: 32-block partials + 1-wave finalize (R7).
// R5 LESSON (kept): no variable-trip inner loops / runtime-indexed
//   ext_vector arrays in k3's sweep -> scratch spill (105MB FETCH, 130x).

#define NT 100000
#define WPR 1568      // padded u64 words per bit-row (1563 real + 5 zero)
#define NWREAL 1563
#define NGRPP 1568    // padded group count
#define NJB 1563      // ceil(NT/64) l1 blocks
#define ETA_MU 55.0f
#define LAM 0.1f

typedef unsigned long long u64;
typedef _Float16 half8 __attribute__((ext_vector_type(8)));
typedef _Float16 half4 __attribute__((ext_vector_type(4)));
typedef float float4v __attribute__((ext_vector_type(4)));

struct __attribute__((aligned(16))) K2aS {
  short sEi[4096];
  _Float16 sXa[64 * 32];
  _Float16 sXb[64 * 32];
};
struct __attribute__((aligned(16))) K3S {
  _Float16 sWt[64 * 136];   // W^T [i][c], c in [0,128), 0-pad c>=100
  _Float16 sGr[64 * 72];    // G rows [i][k] (MFMA-computed)
  float sGd[64];            // diag fp32
  _Float16 sQx[4 * 64 * 72]; // per-wave exchange [jl][i]
};

__device__ inline u64 transpose64(u64 x, int lane) {
  const u64 ms[6] = {0x5555555555555555ull,0x3333333333333333ull,0x0F0F0F0F0F0F0F0Full,
                     0x00FF00FF00FF00FFull,0x0000FFFF0000FFFFull,0x00000000FFFFFFFFull};
#pragma unroll
  for (int si = 0; si < 6; ++si) {
    int s = 1 << si;
    u64 m = ms[si];
    u64 y = __shfl_xor(x, s, 64);
    if ((lane & s) == 0) x = (x & m) | ((y & m) << s);
    else                 x = (x & ~m) | ((y & ~m) >> s);
  }
  return x;
}

__device__ inline double wave_reduce_f64(double v) {
#pragma unroll
  for (int off = 32; off > 0; off >>= 1) v += __shfl_down(v, off, 64);
  return v;
}

// ---------------- phase bodies --------------------------------------------

__device__ __forceinline__ void k1_body(
    int k, int q, const u64* __restrict__ Brow, const u64* __restrict__ Yrow,
    int* __restrict__ S_part, int* __restrict__ R_part) {
  int w0 = q * 196;
  int wv = threadIdx.x >> 6, lane = threadIdx.x & 63;
  u64 tmask = (lane < 4) ? ~0ull : 0ull;
  const u64* bk = Brow + (size_t)k * WPR + w0;
  u64 b0 = bk[lane], b1 = bk[lane + 64], b2 = bk[lane + 128];
  u64 b3 = bk[192 + (lane & 3)] & tmask;
  int sS[16];
#pragma unroll
  for (int m = 0; m < 16; ++m) {
    const u64* br = Brow + (size_t)(4 * m + wv) * WPR + w0;
    u64 x0 = br[lane], x1 = br[lane + 64], x2 = br[lane + 128];
    u64 x3 = br[192 + (lane & 3)] & tmask;
    sS[m] = __popcll(x0 ^ b0) + __popcll(x1 ^ b1) +
            __popcll(x2 ^ b2) + __popcll(x3 ^ b3);
  }
  int sR[25];
#pragma unroll
  for (int m = 0; m < 25; ++m) {
    const u64* yr = Yrow + (size_t)(4 * m + wv) * WPR + w0;
    u64 x0 = yr[lane], x1 = yr[lane + 64], x2 = yr[lane + 128];
    u64 x3 = yr[192 + (lane & 3)] & tmask;
    sR[m] = __popcll(x0 & b0) + __popcll(x1 & b1) +
            __popcll(x2 & b2) + __popcll(x3 & b3);
  }
#pragma unroll
  for (int off = 32; off > 0; off >>= 1) {
#pragma unroll
    for (int m = 0; m < 16; ++m) sS[m] += __shfl_down(sS[m], off, 64);
#pragma unroll
    for (int m = 0; m < 25; ++m) sR[m] += __shfl_down(sR[m], off, 64);
  }
  if (lane == 0) {
#pragma unroll
    for (int m = 0; m < 16; ++m)
      S_part[q * 4096 + k * 64 + 4 * m + wv] = sS[m];
#pragma unroll
    for (int m = 0; m < 25; ++m)
      R_part[q * 6400 + k * 100 + 4 * m + wv] = sR[m];
  }
}

__device__ __forceinline__ void k2a_body(
    int b, const int* __restrict__ S_part, const int* __restrict__ R_part,
    const int* __restrict__ popcY, float* __restrict__ Wr,
    float* __restrict__ Wc, K2aS* __restrict__ s) {
  int tid = threadIdx.x;
  int wv = tid >> 6, k = tid & 63;
  const int qbase_t[4] = {0, 7, 14, 20};
  const int qcnt_t[4]  = {7, 7, 6, 6};
  int qbase = qbase_t[b], Q = qcnt_t[b];
  const int off7[4] = {0, 2, 4, 6}, cnt7[4] = {2, 2, 2, 1};
  const int off6[4] = {0, 2, 4, 5}, cnt6[4] = {2, 2, 1, 1};
  int woff = (Q == 7) ? off7[wv] : off6[wv];
  int wcnt = (Q == 7) ? cnt7[wv] : cnt6[wv];
  const float alpha = 1.0f / (100000.0f + LAM);
  for (int e = tid; e < 4096; e += 256) {
    int kk = e >> 6, ll = e & 63;
    int mm = 0;
#pragma unroll
    for (int qq = 0; qq < 8; ++qq) mm += S_part[qq * 4096 + e];
    int v = (kk == ll) ? 0 : (NT - 2 * mm);
    v = v > 32767 ? 32767 : (v < -32767 ? -32767 : v);
    s->sEi[kk * 64 + (ll ^ (kk & 31))] = (short)v;
  }
  float4 rr4[2], xf[2];
#pragma unroll
  for (int q = 0; q < 2; ++q) {
    if (q < wcnt) {
      float tmp[4];
#pragma unroll
      for (int e4 = 0; e4 < 4; ++e4) {
        int cg2 = 4 * (qbase + woff + q) + e4;
        float rv = 0.0f;
        if (cg2 < 100) {
          int rr = 0;
#pragma unroll
          for (int qq = 0; qq < 8; ++qq) rr += R_part[qq * 6400 + k * 100 + cg2];
          rv = (float)(2 * rr - popcY[cg2]);
        }
        tmp[e4] = rv;
      }
      rr4[q] = make_float4(tmp[0], tmp[1], tmp[2], tmp[3]);
      xf[q] = make_float4(alpha * tmp[0], alpha * tmp[1],
                          alpha * tmp[2], alpha * tmp[3]);
    }
  }
  if (wcnt == 2) {
    half8 h;
    h[0] = (_Float16)xf[0].x; h[1] = (_Float16)xf[0].y;
    h[2] = (_Float16)xf[0].z; h[3] = (_Float16)xf[0].w;
    h[4] = (_Float16)xf[1].x; h[5] = (_Float16)xf[1].y;
    h[6] = (_Float16)xf[1].z; h[7] = (_Float16)xf[1].w;
    *(half8*)&s->sXa[k * 32 + 4 * woff] = h;
  } else {
    half4 h;
    h[0] = (_Float16)xf[0].x; h[1] = (_Float16)xf[0].y;
    h[2] = (_Float16)xf[0].z; h[3] = (_Float16)xf[0].w;
    *(half4*)&s->sXa[k * 32 + 4 * woff] = h;
  }
  __syncthreads();
  _Float16* Xs = s->sXa;
  _Float16* Xd = s->sXb;
  for (int it2 = 0; it2 < 4; ++it2) {
    float4 a4[2];
#pragma unroll
    for (int q = 0; q < 2; ++q)
      if (q < wcnt) a4[q] = rr4[q];
    if (wcnt == 2) {
      for (int l = 0; l < 64; ++l) {
        float ev = (float)s->sEi[k * 64 + (l ^ (k & 31))];
        half8 x8 = *(const half8*)&Xs[l * 32 + 4 * woff];
        a4[0].x -= ev * (float)x8[0]; a4[0].y -= ev * (float)x8[1];
        a4[0].z -= ev * (float)x8[2]; a4[0].w -= ev * (float)x8[3];
        a4[1].x -= ev * (float)x8[4]; a4[1].y -= ev * (float)x8[5];
        a4[1].z -= ev * (float)x8[6]; a4[1].w -= ev * (float)x8[7];
      }
    } else {
      for (int l = 0; l < 64; ++l) {
        float ev = (float)s->sEi[k * 64 + (l ^ (k & 31))];
        half4 x4 = *(const half4*)&Xs[l * 32 + 4 * woff];
        a4[0].x -= ev * (float)x4[0]; a4[0].y -= ev * (float)x4[1];
        a4[0].z -= ev * (float)x4[2]; a4[0].w -= ev * (float)x4[3];
      }
    }
#pragma unroll
    for (int q = 0; q < 2; ++q) {
      if (q < wcnt) {
        xf[q] = make_float4(alpha * a4[q].x, alpha * a4[q].y,
                            alpha * a4[q].z, alpha * a4[q].w);
      }
    }
    if (it2 < 3) {
      if (wcnt == 2) {
        half8 h;
        h[0] = (_Float16)xf[0].x; h[1] = (_Float16)xf[0].y;
        h[2] = (_Float16)xf[0].z; h[3] = (_Float16)xf[0].w;
        h[4] = (_Float16)xf[1].x; h[5] = (_Float16)xf[1].y;
        h[6] = (_Float16)xf[1].z; h[7] = (_Float16)xf[1].w;
        *(half8*)&Xd[k * 32 + 4 * woff] = h;
      } else {
        half4 h;
        h[0] = (_Float16)xf[0].x; h[1] = (_Float16)xf[0].y;
        h[2] = (_Float16)xf[0].z; h[3] = (_Float16)xf[0].w;
        *(half4*)&Xd[k * 32 + 4 * woff] = h;
      }
      __syncthreads();
      _Float16* t = Xs; Xs = Xd; Xd = t;
    }
  }
#pragma unroll
  for (int q = 0; q < 2; ++q) {
    if (q < wcnt) {
      float v4[4] = {xf[q].x, xf[q].y, xf[q].z, xf[q].w};
#pragma unroll
      for (int e4 = 0; e4 < 4; ++e4) {
        int cg2 = 4 * (qbase + woff + q) + e4;
        if (cg2 < 100) {
          Wr[k * 100 + cg2] = v4[e4];
          Wc[cg2 * 64 + k] = v4[e4];
        }
      }
    }
  }
}

__device__ __forceinline__ void k3_body(
    int bid, int it, const float* __restrict__ U, const float* __restrict__ u,
    const signed char* __restrict__ owner, const float* __restrict__ Wc,
    u64* __restrict__ Bmask, u64* __restrict__ Brow,
    const u64* __restrict__ Ymask, int* __restrict__ cflags,
    K3S* __restrict__ s) {
  int tid = threadIdx.x;
  for (int t = tid; t < 8192; t += 256) {
    int i = t & 63, c = t >> 6;
    s->sWt[i * 136 + c] = (c < 100) ? (_Float16)Wc[c * 64 + i] : (_Float16)0.0f;
  }
  __syncthreads();
  int wv = tid >> 6, lane = tid & 63;
  int g = bid * 4 + wv;
  int n15 = lane & 15, quad = lane >> 4;
  int j = g * 64 + lane;
  bool act = j < NT;
  int jc = act ? j : NT - 1;
  u64 bm = Bmask[jc];
  u64 y0 = Ymask[2 * jc], y1 = Ymask[2 * jc + 1];
  half8 aW[4][4];
#pragma unroll
  for (int mt = 0; mt < 4; ++mt) {
    int rb = mt * 16 + n15;
#pragma unroll
    for (int kt = 0; kt < 4; ++kt)
      aW[mt][kt] = *(const half8*)&s->sWt[rb * 136 + kt * 32 + quad * 8];
  }
  half8 aWv[4];
  {
    int rb = wv * 16 + n15;
#pragma unroll
    for (int kt = 0; kt < 4; ++kt)
      aWv[kt] = *(const half8*)&s->sWt[rb * 136 + kt * 32 + quad * 8];
  }
#pragma unroll
  for (int nt = 0; nt < 4; ++nt) {
    float4v c = {0.f, 0.f, 0.f, 0.f};
#pragma unroll
    for (int kt = 0; kt < 4; ++kt)
      c = __builtin_amdgcn_mfma_f32_16x16x32_f16(aWv[kt], aW[nt][kt], c, 0, 0, 0);
#pragma unroll
    for (int r = 0; r < 4; ++r) {
      int gi = wv * 16 + quad * 4 + r;
      int gk = nt * 16 + n15;
      s->sGr[gi * 72 + gk] = (_Float16)c[r];
      if (gk == gi) s->sGd[gi] = c[r];
    }
  }
  __syncthreads();   // G complete for all waves
  half8 aG[4][2];
#pragma unroll
  for (int mt = 0; mt < 4; ++mt) {
    int rb = mt * 16 + n15;
#pragma unroll
    for (int kt = 0; kt < 2; ++kt)
      aG[mt][kt] = *(const half8*)&s->sGr[rb * 72 + kt * 32 + quad * 8];
  }
  _Float16* xq = &s->sQx[wv * 64 * 72];
  int c0q = quad * 8;
#pragma unroll
  for (int nt = 0; nt < 4; ++nt) {
    int src = nt * 16 + n15;
    u64 cy0 = __shfl(y0, src, 64);
    u64 cy1 = __shfl(y1, src, 64);
    u64 cbm = __shfl(bm, src, 64);
    half8 yf[4], bf[2];
#pragma unroll
    for (int kt = 0; kt < 2; ++kt) {           // classes [0,64)
      int c0 = kt * 32 + c0q;
      u64 w = cy0 >> c0;
      w |= (c0 ? (cy1 << ((64 - c0) & 63)) : 0ull);
#pragma unroll
      for (int e = 0; e < 8; ++e)
        yf[kt][e] = ((w >> e) & 1ull) ? (_Float16)1.0f : (_Float16)0.0f;
    }
#pragma unroll
    for (int kt = 2; kt < 4; ++kt) {           // classes [64,128), >=100 zero
      int c0 = (kt - 2) * 32 + c0q;
      u64 w = cy1 >> c0;
#pragma unroll
      for (int e = 0; e < 8; ++e)
        yf[kt][e] = ((w >> e) & 1ull) ? (_Float16)1.0f : (_Float16)0.0f;
    }
#pragma unroll
    for (int kt = 0; kt < 2; ++kt) {           // -b: bit -> -1, else +1
      int c0 = kt * 32 + c0q;
      u64 w = cbm >> c0;
#pragma unroll
      for (int e = 0; e < 8; ++e)
        bf[kt][e] = ((w >> e) & 1ull) ? (_Float16)-1.0f : (_Float16)1.0f;
    }
#pragma unroll
    for (int mt = 0; mt < 4; ++mt) {
      float4v c = {0.f, 0.f, 0.f, 0.f};
#pragma unroll
      for (int kt = 0; kt < 4; ++kt)
        c = __builtin_amdgcn_mfma_f32_16x16x32_f16(aW[mt][kt], yf[kt], c, 0, 0, 0);
#pragma unroll
      for (int kt = 0; kt < 2; ++kt)
        c = __builtin_amdgcn_mfma_f32_16x16x32_f16(aG[mt][kt], bf[kt], c, 0, 0, 0);
      half4 hs;
      hs[0] = (_Float16)c[0]; hs[1] = (_Float16)c[1];
      hs[2] = (_Float16)c[2]; hs[3] = (_Float16)c[3];
      *(half4*)&xq[(nt * 16 + n15) * 72 + mt * 16 + quad * 4] = hs;
    }
  }
  // wave-internal exchange: compiler-inserted lgkmcnt orders write->read
  int ow = owner[jc];
  float p[64];
  if (ow >= 0) {
#pragma unroll
    for (int i = 0; i < 64; ++i) p[i] = ETA_MU * u[ow * 64 + i];
  } else {
#pragma unroll
    for (int i = 0; i < 64; ++i) p[i] = ETA_MU * U[(size_t)i * NT + jc];
  }
  half8 qx[8];
#pragma unroll
  for (int t = 0; t < 8; ++t)
    qx[t] = *(const half8*)&xq[lane * 72 + t * 8];
  // sequential GS sweep; packed fixed-trip repair on flips (R6 shape)
  u64 cm = bm;
#pragma unroll
  for (int i = 0; i < 64; ++i) {
    bool ob = (cm >> i) & 1ull;
    float val = p[i] + (float)qx[i >> 3][i & 7] + (ob ? s->sGd[i] : -s->sGd[i]);
    bool nb = val > 0.0f;
    bool ch = (nb != ob);
    if (__any(ch)) {
      _Float16 dl = ch ? (nb ? (_Float16)2.0f : (_Float16)-2.0f) : (_Float16)0.0f;
#pragma unroll
      for (int t = 0; t < 8; ++t) {
        half8 gr = *(const half8*)&s->sGr[i * 72 + t * 8];   // uniform broadcast
        qx[t] -= gr * dl;
      }
      if (ch) cm ^= (1ull << i);
    }
  }
  u64 nm = act ? cm : 0ull;
  bool chg = act && (nm != bm);
  if (__any(chg) && lane == 0) cflags[it] = 1;
  if (act) Bmask[j] = nm;
  u64 tb = transpose64(nm, lane);
  Brow[(size_t)lane * WPR + g] = tb;
}

// ---------------- prologue (R9: fused 3 -> 2 kernels) ----------------------

// scatter_pre: batch y-masks, colmap = ind, zero popcY + cflags.
__global__ void scatter_pre(const float* __restrict__ y,
                            const int* __restrict__ ind,
                            u64* __restrict__ ybatch, int* __restrict__ colmap,
                            int* __restrict__ popcY, int* __restrict__ cflags) {
  int b = threadIdx.x;   // 128 threads
  if (b < 16) cflags[b] = 0;
  if (b < 100) popcY[b] = 0;
  if (b >= 128) return;
  u64 m0 = 0, m1 = 0;
  for (int c = 0; c < 100; ++c) {
    bool v = y[b * 100 + c] > 0.5f;
    if (c < 64) m0 |= ((u64)v) << c;
    else        m1 |= ((u64)v) << (c - 64);
  }
  ybatch[2 * b] = m0;
  ybatch[2 * b + 1] = m1;
  colmap[b] = ind[b];
}

// build_all: column masks from B/Ybuf with inline scatter substitution
// (LDS colmap lookup), owner, and in-register transpose -> bit planes +
// popcY atomics. Grid 392 covers all NGRPP=1568 groups (block 391 = pad).
__global__ __launch_bounds__(256) void build_all(
    const float* __restrict__ B, const float* __restrict__ Ybuf,
    const int* __restrict__ colmap, const u64* __restrict__ ybatch,
    u64* __restrict__ Bmask, u64* __restrict__ Ymask,
    u64* __restrict__ Brow, u64* __restrict__ Yrow,
    signed char* __restrict__ owner, int* __restrict__ popcY) {
  __shared__ int sind[128];
  __shared__ u64 syb[256];
  int tid = threadIdx.x;
  if (tid < 128) sind[tid] = colmap[tid];
  syb[tid] = ybatch[tid];
  __syncthreads();
  int j = blockIdx.x * 256 + tid;
  int lane = tid & 63;
  int g = blockIdx.x * 4 + (tid >> 6);   // g < 1568
  bool act = j < NT;
  u64 bm = 0, m0 = 0, m1 = 0;
  if (act) {
#pragma unroll
    for (int i = 0; i < 64; ++i)
      bm |= ((u64)(B[(size_t)i * NT + j] > 0.0f)) << i;
#pragma unroll
    for (int c = 0; c < 64; ++c)
      m0 |= ((u64)(Ybuf[(size_t)c * NT + j] > 0.5f)) << c;
#pragma unroll
    for (int c = 64; c < 100; ++c)
      m1 |= ((u64)(Ybuf[(size_t)c * NT + j] > 0.5f)) << (c - 64);
    int own = -1;
    for (int b2 = 0; b2 < 128; ++b2)
      if (sind[b2] == j) own = b2;
    if (own >= 0) { m0 = syb[2 * own]; m1 = syb[2 * own + 1]; }
    owner[j] = (signed char)own;
    Bmask[j] = bm;
    Ymask[2 * j] = m0;
    Ymask[2 * j + 1] = m1;
  }
  u64 tb = transpose64(bm, lane);
  Brow[(size_t)lane * WPR + g] = tb;
  u64 t0 = transpose64(m0, lane);
  Yrow[(size_t)lane * WPR + g] = t0;
  atomicAdd(&popcY[lane], (int)__popcll(t0));
  u64 t1 = transpose64(m1, lane);
  if (lane < 36) {
    Yrow[(size_t)(64 + lane) * WPR + g] = t1;
    atomicAdd(&popcY[64 + lane], (int)__popcll(t1));
  }
}

// ---------------- loop kernels (classic; R1 cflags skip) ------------------

__global__ __launch_bounds__(256, 4) void k1_sr(
    const u64* __restrict__ Brow, const u64* __restrict__ Yrow,
    int* __restrict__ S_part, int* __restrict__ R_part,
    int it, const int* __restrict__ cflags) {
  if (it > 0 && cflags[it - 1] == 0) return;
  k1_body(blockIdx.x, blockIdx.y, Brow, Yrow, S_part, R_part);
}

__global__ __launch_bounds__(256, 1) void k2a_solve(
    const int* __restrict__ S_part, const int* __restrict__ R_part,
    const int* __restrict__ popcY, float* __restrict__ Wr,
    float* __restrict__ Wc, int it, const int* __restrict__ cflags) {
  if (it > 0 && cflags[it - 1] == 0) return;
  __shared__ K2aS s;
  k2a_body(blockIdx.x, S_part, R_part, popcY, Wr, Wc, &s);
}

__global__ __launch_bounds__(256, 2) void k3_gs(
    const float* __restrict__ U, const float* __restrict__ u,
    const signed char* __restrict__ owner, const float* __restrict__ Wc,
    u64* __restrict__ Bmask, u64* __restrict__ Brow,
    const u64* __restrict__ Ymask, int it, int* __restrict__ cflags) {
  if (it > 0 && cflags[it - 1] == 0) return;
  __shared__ K3S s;
  k3_body(blockIdx.x, it, U, u, owner, Wc, Bmask, Brow, Ymask, cflags, &s);
}

// ---------------- epilogue kernels ----------------------------------------

__global__ __launch_bounds__(256, 4) void l1_like(
    const float* __restrict__ U, const float* __restrict__ u,
    const signed char* __restrict__ owner, const u64* __restrict__ Ymask,
    const u64* __restrict__ ybatch, double* __restrict__ partial) {
  __shared__ _Float16 shu[8192];   // u fp16, row b: k8 stored at (k8 ^ (b&7))
  __shared__ u64 sy[256];
  __shared__ double wred[4];
  int tid = threadIdx.x;
  for (int e = tid; e < 1024; e += 256) {
    int b = e >> 3, k8 = e & 7;
    const float4* src = (const float4*)&u[b * 64 + k8 * 8];
    float4 f0 = src[0], f1 = src[1];
    half8 h;
    h[0] = (_Float16)f0.x; h[1] = (_Float16)f0.y;
    h[2] = (_Float16)f0.z; h[3] = (_Float16)f0.w;
    h[4] = (_Float16)f1.x; h[5] = (_Float16)f1.y;
    h[6] = (_Float16)f1.z; h[7] = (_Float16)f1.w;
    *(half8*)&shu[b * 64 + ((k8 ^ (b & 7)) * 8)] = h;
  }
  if (tid < 256) sy[tid] = ybatch[tid];
  __syncthreads();
  int wv = tid >> 6, lane = tid & 63;
  int n = lane & 15, q = lane >> 4;
  int j = blockIdx.x * 64 + wv * 16 + n;
  bool actj = j < NT;
  int jc = actj ? j : NT - 1;
  int ow = owner[jc];
  half8 bf0, bf1;
#pragma unroll
  for (int t = 0; t < 8; ++t) {
    int k = q * 8 + t;
    bf0[t] = (_Float16)U[(size_t)k * NT + jc];
    bf1[t] = (_Float16)U[(size_t)(k + 32) * NT + jc];
  }
  if (ow >= 0) {
#pragma unroll
    for (int t = 0; t < 8; ++t) {
      bf0[t] = (_Float16)u[ow * 64 + q * 8 + t];
      bf1[t] = (_Float16)u[ow * 64 + 32 + q * 8 + t];
    }
  }
  u64 ym0 = Ymask[2 * jc], ym1 = Ymask[2 * jc + 1];
  float lsum = 0.0f;
#pragma unroll
  for (int t8 = 0; t8 < 8; ++t8) {
    int brow = t8 * 16 + n;
    half8 a0 = *(const half8*)&shu[brow * 64 + ((q ^ (brow & 7)) * 8)];
    half8 a1 = *(const half8*)&shu[brow * 64 + (((q + 4) ^ (brow & 7)) * 8)];
    float4v c = {0.f, 0.f, 0.f, 0.f};
    c = __builtin_amdgcn_mfma_f32_16x16x32_f16(a0, bf0, c, 0, 0, 0);
    c = __builtin_amdgcn_mfma_f32_16x16x32_f16(a1, bf1, c, 0, 0, 0);
#pragma unroll
    for (int r = 0; r < 4; ++r) {
      int b = t8 * 16 + q * 4 + r;
      float ip = 0.5f * c[r];
      u64 yb0 = sy[2 * b], yb1 = sy[2 * b + 1];
      bool s = ((yb0 & ym0) | (yb1 & ym1)) != 0ull;
      float a = fabsf(ip);
      lsum += __logf(1.0f + __expf(-a)) + fmaxf(ip, 0.0f) - (s ? ip : 0.0f);
    }
  }
  if (!actj) lsum = 0.0f;
  double lsd = wave_reduce_f64((double)lsum);
  if (lane == 0) wred[wv] = lsd;
  __syncthreads();
  if (tid == 0)
    partial[blockIdx.x] = wred[0] + wred[1] + wred[2] + wred[3];
}

__global__ __launch_bounds__(256) void l2_part(
    const float* __restrict__ Wr, const float* __restrict__ y,
    const int* __restrict__ ind, const u64* __restrict__ Bmask,
    const double* __restrict__ partial, double* __restrict__ part3) {
  __shared__ float sw[6400];
  __shared__ u64 sbm[128];
  __shared__ double dred[12];
  int tid = threadIdx.x, bid = blockIdx.x;
  for (int t = tid; t < 6400; t += 256) sw[t] = Wr[t];
  if (tid < 128) sbm[tid] = Bmask[ind[tid]];
  __syncthreads();
  double cls = 0.0, regs = 0.0, l1s = 0.0;
  int e0 = bid * 400;                      // 32 x 400 = 12800
  for (int e = e0 + tid; e < e0 + 400; e += 256) {
    int c = e >> 7, b = e & 127;
    u64 bm = sbm[b];
    float s = 0.0f;
#pragma unroll
    for (int i = 0; i < 64; ++i) {
      float w = sw[i * 100 + c];
      s += ((bm >> i) & 1ull) ? w : -w;
    }
    float d = y[b * 100 + c] - s;
    cls += (double)(d * d);
  }
  int r0 = bid * 200;                      // 32 x 200 = 6400
  for (int e = r0 + tid; e < r0 + 200; e += 256) {
    float w = sw[e];
    regs += (double)(w * w);
  }
  int t = bid * 256 + tid;                 // 32 x 256 = 8192 >= NJB
  if (t < NJB) l1s = partial[t];
  cls = wave_reduce_f64(cls);
  regs = wave_reduce_f64(regs);
  l1s = wave_reduce_f64(l1s);
  int wv = tid >> 6;
  if ((tid & 63) == 0) { dred[wv] = cls; dred[4 + wv] = regs; dred[8 + wv] = l1s; }
  __syncthreads();
  if (tid == 0) {
    part3[bid * 4 + 0] = dred[0] + dred[1] + dred[2] + dred[3];
    part3[bid * 4 + 1] = dred[4] + dred[5] + dred[6] + dred[7];
    part3[bid * 4 + 2] = dred[8] + dred[9] + dred[10] + dred[11];
  }
}

__global__ void l2_fin2(const double* __restrict__ part3,
                        float* __restrict__ out) {
  int tid = threadIdx.x;   // 64 threads
  double c = 0.0, r = 0.0, l = 0.0;
  if (tid < 32) {
    c = part3[tid * 4 + 0];
    r = part3[tid * 4 + 1];
    l = part3[tid * 4 + 2];
  }
  c = wave_reduce_f64(c);
  r = wave_reduce_f64(r);
  l = wave_reduce_f64(l);
  if (tid == 0)
    out[0] = (float)(l * (1.0 / 12800000.0) + c * (1.0 / 12800.0) +
                     r * (0.1 / 6400.0));
}

extern "C" void kernel_launch(void* const* d_in, const int* in_sizes, int n_in,
                              void* d_out, int out_size, void* d_ws, size_t ws_size,
                              hipStream_t stream) {
  const float* u    = (const float*)d_in[0];
  const float* y    = (const float*)d_in[1];
  const int*   ind  = (const int*)d_in[2];
  const float* U    = (const float*)d_in[3];
  const float* B    = (const float*)d_in[4];
  const float* Ybuf = (const float*)d_in[5];
  char* ws = (char*)d_ws;
  int* cflags        = (int*)ws;               // 16 ints in bytes [0,64)
  u64* Bmask         = (u64*)(ws + 256);
  u64* Ymask         = (u64*)(ws + 800256);
  u64* Brow          = (u64*)(ws + 2400256);
  u64* Yrow          = (u64*)(ws + 3203072);
  u64* ybatch        = (u64*)(ws + 4457472);
  int* popcY         = (int*)(ws + 4459520);
  int* S_part        = (int*)(ws + 4460032);   // 8*4096 ints
  int* R_part        = (int*)(ws + 4591104);   // 8*6400 ints
  float* Wr          = (float*)(ws + 4795904);
  float* Wc          = (float*)(ws + 4821504);
  double* part3      = (double*)(ws + 4847104); // 32*4 doubles
  int* colmap        = (int*)(ws + 4855296);    // 128 ints
  signed char* owner = (signed char*)(ws + 4863488);
  double* partial    = (double*)(ws + 4963520); // NJB doubles

  scatter_pre<<<1, 128, 0, stream>>>(y, ind, ybatch, colmap, popcY, cflags);
  build_all<<<392, 256, 0, stream>>>(B, Ybuf, colmap, ybatch, Bmask, Ymask,
                                     Brow, Yrow, owner, popcY);
  for (int it = 0; it < 10; ++it) {
    k1_sr<<<dim3(64, 8), 256, 0, stream>>>(Brow, Yrow, S_part, R_part, it, cflags);
    k2a_solve<<<4, 256, 0, stream>>>(S_part, R_part, popcY, Wr, Wc, it, cflags);
    k3_gs<<<392, 256, 0, stream>>>(U, u, owner, Wc, Bmask, Brow, Ymask, it, cflags);
  }
  l1_like<<<NJB, 256, 0, stream>>>(U, u, owner, Ymask, ybatch, partial);
  l2_part<<<32, 256, 0, stream>>>(Wr, y, ind, Bmask, partial, part3);
  l2_fin2<<<1, 64, 0, stream>>>(part3, (float*)d_out);
}